// Round 2
// baseline (207.700 us; speedup 1.0000x reference)
//
#include <hip/hip_runtime.h>
#include <hip/hip_bf16.h>

#define NF 40
#define NE 128
#define NA 128
#define NP 780        // NF*(NF-1)/2
#define NPT 800       // padded to 25*32
#define NMT 25        // m-tiles of 32 pairs
#define NTH 512       // 8 waves: waves 0-3 -> batch elem 0, waves 4-7 -> batch elem 1

typedef short short8 __attribute__((ext_vector_type(8)));
typedef float floatx16 __attribute__((ext_vector_type(16)));
typedef unsigned int uint32;

__device__ __forceinline__ float bflo(uint32 u) {
    union { uint32 u; float f; } c; c.u = u << 16; return c.f;
}
__device__ __forceinline__ float bfhi(uint32 u) {
    union { uint32 u; float f; } c; c.u = u & 0xFFFF0000u; return c.f;
}
__device__ __forceinline__ unsigned short f2bf(float f) {
    union { float f; uint32 u; } v; v.f = f;
    uint32 r = v.u + 0x7FFFu + ((v.u >> 16) & 1u);   // RNE
    return (unsigned short)(r >> 16);
}

#if defined(__has_builtin)
#if __has_builtin(__builtin_amdgcn_cvt_pk_bf16_f32)
#define HAVE_CVT_PK_BF16 1
#endif
#endif

typedef __bf16 vbf2 __attribute__((ext_vector_type(2)));
__device__ __forceinline__ uint32 pkbf(float lo, float hi) {
#ifdef HAVE_CVT_PK_BF16
    union { vbf2 v; uint32 u; } c;
    c.v = __builtin_amdgcn_cvt_pk_bf16_f32(lo, hi);
    return c.u;
#else
    return ((uint32)f2bf(hi) << 16) | (uint32)f2bf(lo);
#endif
}
// packed "bf16 multiply": dwords a,b each hold 2 bf16; product rounded to 2 bf16
__device__ __forceinline__ uint32 pkmul(uint32 a, uint32 b) {
    return pkbf(bflo(a) * bflo(b), bfhi(a) * bfhi(b));
}

union ShmU {
    unsigned short ws[NA * NE];   // 32768 B: swizzled bf16 W, live through MFMA phase
    float afmp[2][16][NE];        // 16384 B: afm partials, live after softmax
};
union U4S8 { uint4 u; short8 s; };

// XOR swizzle: 16B blocks (8 bf16) at block index kb stored at kb ^ (row & 15).
// B-frag reads then hit each 4-bank group exactly 2x (free per m136).

__global__ __launch_bounds__(NTH, 4)
void afm_fused2(const float* __restrict__ xg,   // [B, F, E]
                const float* __restrict__ wg,   // [A, E]
                const float* __restrict__ wbg,  // [A]
                const float* __restrict__ hg,   // [1, A]
                const float* __restrict__ pwg,  // [1, E]
                const float* __restrict__ pbg,  // [1]
                float* __restrict__ out)        // [B]
{
    __shared__ ShmU u;
    __shared__ unsigned short xsb[2][NF * NE];  // 20480 B swizzled bf16 x
    __shared__ float sc[2][NPT];                // 6400 B
    __shared__ unsigned short ij[NPT];          // 1600 B packed (i<<8)|j
    __shared__ float redm[2][4], reds[2][4], redo[2][2];

    const int tid = threadIdx.x;
    const int b0  = blockIdx.x * 2;

    // ---- stage W as swizzled bf16 (128 rows x 16 blocks of 8) ----
    for (int t = tid; t < NA * 16; t += NTH) {
        int row = t >> 4, kb = t & 15;
        const float* src = wg + row * NE + kb * 8;
        float4 v0 = *(const float4*)src;
        float4 v1 = *(const float4*)(src + 4);
        uint4 d;
        d.x = pkbf(v0.x, v0.y); d.y = pkbf(v0.z, v0.w);
        d.z = pkbf(v1.x, v1.y); d.w = pkbf(v1.z, v1.w);
        *(uint4*)&u.ws[row * NE + ((kb ^ (row & 15)) * 8)] = d;
    }
    // ---- stage x (both batch elems) as swizzled bf16 ----
    for (int t = tid; t < 2 * NF * 16; t += NTH) {
        int bb = (t >= NF * 16) ? 1 : 0;
        int tt = t - bb * NF * 16;
        int row = tt >> 4, kb = tt & 15;
        const float* src = xg + (size_t)(b0 + bb) * (NF * NE) + row * NE + kb * 8;
        float4 v0 = *(const float4*)src;
        float4 v1 = *(const float4*)(src + 4);
        uint4 d;
        d.x = pkbf(v0.x, v0.y); d.y = pkbf(v0.z, v0.w);
        d.z = pkbf(v1.x, v1.y); d.w = pkbf(v1.z, v1.w);
        *(uint4*)&xsb[bb][row * NE + ((kb ^ (row & 15)) * 8)] = d;
    }
    // ---- pair index table (shared by both batch elems) ----
    for (int p = tid; p < NPT; p += NTH) {
        unsigned short v = 0;
        if (p < NP) {
            int i = 0, rem = p;
            while (rem >= (NF - 1 - i)) { rem -= (NF - 1 - i); ++i; }
            v = (unsigned short)((i << 8) | (i + 1 + rem));
        }
        ij[p] = v;
    }
    __syncthreads();

    // =================== MFMA phase: S[p,a], scores ===================
    const int wid  = tid >> 6;
    const int lane = tid & 63;
    const int bh   = wid >> 2;        // batch half
    const int wloc = wid & 3;
    const int col  = lane & 31;       // a-col within n-tile / pair-row selector
    const int half = lane >> 5;       // k-half
    const unsigned short* xb = xsb[bh];
    const int swb = col & 15;         // W swizzle key for this lane's B rows

    float wbr[4], hr[4];
#pragma unroll
    for (int n = 0; n < 4; ++n) {
        wbr[n] = wbg[n * 32 + col];
        hr[n]  = hg[n * 32 + col];
    }

    for (int mt = wloc; mt < NMT; mt += 4) {
        const int p0 = mt * 32;
        const int v  = ij[p0 + col];
        const int fi = (v >> 8) & 255, fj = v & 255;
        const unsigned short* xi = xb + fi * NE;
        const unsigned short* xj = xb + fj * NE;
        const int swi = fi & 15, swj = fj & 15;

        floatx16 acc[4];
#pragma unroll
        for (int n = 0; n < 4; ++n)
#pragma unroll
            for (int r = 0; r < 16; ++r) acc[n][r] = 0.f;

#pragma unroll
        for (int k = 0; k < 8; ++k) {
            const int kb = 2 * k + half;   // 16B block covering e = 16k + 8*half ..+8
            U4S8 ai, aj, af;
            ai.u = *(const uint4*)(xi + ((kb ^ swi) * 8));
            aj.u = *(const uint4*)(xj + ((kb ^ swj) * 8));
            af.u.x = pkmul(ai.u.x, aj.u.x);
            af.u.y = pkmul(ai.u.y, aj.u.y);
            af.u.z = pkmul(ai.u.z, aj.u.z);
            af.u.w = pkmul(ai.u.w, aj.u.w);
#pragma unroll
            for (int n = 0; n < 4; ++n) {
                U4S8 bf;
                bf.u = *(const uint4*)&u.ws[(n * 32 + col) * NE + ((kb ^ swb) * 8)];
                acc[n] = __builtin_amdgcn_mfma_f32_32x32x16_bf16(af.s, bf.s, acc[n], 0, 0, 0);
            }
        }

        // scores[p] = sum_a relu(S[p,a] + wb[a]) * h[a]   (h_b cancels in softmax)
        float ps[16];
#pragma unroll
        for (int r = 0; r < 16; ++r) {
            float s = 0.f;
#pragma unroll
            for (int n = 0; n < 4; ++n) {
                float val = acc[n][r] + wbr[n];
                s += fmaxf(val, 0.f) * hr[n];
            }
#pragma unroll
            for (int off = 1; off < 32; off <<= 1)
                s += __shfl_xor(s, off);
            ps[r] = s;
        }
        if (col == 0) {
#pragma unroll
            for (int r = 0; r < 16; ++r) {
                int row = (r & 3) + 8 * (r >> 2) + 4 * half;
                int pp  = p0 + row;
                if (pp < NP) sc[bh][pp] = ps[r];
            }
        }
    }
    __syncthreads();

    // =================== softmax over 780 pairs (per batch half) ===================
    const int bh2 = tid >> 8;       // 0 or 1
    const int t2  = tid & 255;
    const int w2  = t2 >> 6;

    float m = -1e30f;
    for (int p = t2; p < NP; p += 256) m = fmaxf(m, sc[bh2][p]);
#pragma unroll
    for (int off = 1; off < 64; off <<= 1) m = fmaxf(m, __shfl_xor(m, off));
    if ((t2 & 63) == 0) redm[bh2][w2] = m;
    __syncthreads();
    const float M = fmaxf(fmaxf(redm[bh2][0], redm[bh2][1]),
                          fmaxf(redm[bh2][2], redm[bh2][3]));

    float s = 0.f;
    for (int p = t2; p < NP; p += 256) {
        float e = __expf(sc[bh2][p] - M);
        sc[bh2][p] = e;
        s += e;
    }
#pragma unroll
    for (int off = 1; off < 64; off <<= 1) s += __shfl_xor(s, off);
    if ((t2 & 63) == 0) reds[bh2][w2] = s;
    __syncthreads();   // exp values visible; W in u.ws now dead -> afmp may be written

    // =================== afm[e] = sum_p exp_p * xi[e]*xj[e] ===================
    const int q  = t2 >> 4;         // 16 pair-chunks of <=49
    const int kb = t2 & 15;         // 8-element e-block
    float a[8];
#pragma unroll
    for (int r = 0; r < 8; ++r) a[r] = 0.f;
    const unsigned short* xb2 = xsb[bh2];
    const int pbeg = q * 49;
    const int pend = (pbeg + 49 < NP) ? (pbeg + 49) : NP;
    for (int p = pbeg; p < pend; ++p) {
        int vv = ij[p];
        float w = sc[bh2][p];
        int fi = (vv >> 8) & 255, fj = vv & 255;
        uint4 ri = *(const uint4*)(xb2 + fi * NE + ((kb ^ (fi & 15)) * 8));
        uint4 rj = *(const uint4*)(xb2 + fj * NE + ((kb ^ (fj & 15)) * 8));
        a[0] += w * (bflo(ri.x) * bflo(rj.x));
        a[1] += w * (bfhi(ri.x) * bfhi(rj.x));
        a[2] += w * (bflo(ri.y) * bflo(rj.y));
        a[3] += w * (bfhi(ri.y) * bfhi(rj.y));
        a[4] += w * (bflo(ri.z) * bflo(rj.z));
        a[5] += w * (bfhi(ri.z) * bfhi(rj.z));
        a[6] += w * (bflo(ri.w) * bflo(rj.w));
        a[7] += w * (bfhi(ri.w) * bfhi(rj.w));
    }
    *(float4*)&u.afmp[bh2][q][kb * 8]     = make_float4(a[0], a[1], a[2], a[3]);
    *(float4*)&u.afmp[bh2][q][kb * 8 + 4] = make_float4(a[4], a[5], a[6], a[7]);
    __syncthreads();

    // ---- out[b] = dot(afm_un, pw) / sum_exp + p_b ----
    float vv2 = 0.f;
    if (t2 < NE) {
        float acc2 = 0.f;
#pragma unroll
        for (int qq = 0; qq < 16; ++qq) acc2 += u.afmp[bh2][qq][t2];
        vv2 = acc2 * pwg[t2];
    }
#pragma unroll
    for (int off = 1; off < 64; off <<= 1) vv2 += __shfl_xor(vv2, off);
    if (t2 < NE && (t2 & 63) == 0) redo[bh2][t2 >> 6] = vv2;
    __syncthreads();
    if (t2 == 0) {
        float S   = reds[bh2][0] + reds[bh2][1] + reds[bh2][2] + reds[bh2][3];
        float tot = redo[bh2][0] + redo[bh2][1];
        out[b0 + bh2] = tot / S + pbg[0];
    }
}

extern "C" void kernel_launch(void* const* d_in, const int* in_sizes, int n_in,
                              void* d_out, int out_size, void* d_ws, size_t ws_size,
                              hipStream_t stream) {
    const float* xg  = (const float*)d_in[0];  // x [B,F,E]
    const float* wg  = (const float*)d_in[1];  // attn_w_w [A,E]
    const float* wbg = (const float*)d_in[2];  // attn_w_b [A]
    const float* hg  = (const float*)d_in[3];  // attn_h_w [1,A]
    // d_in[4] = attn_h_b : constant shift, cancels in softmax
    const float* pwg = (const float*)d_in[5];  // attn_p_w [1,E]
    const float* pbg = (const float*)d_in[6];  // attn_p_b [1]
    const int B = in_sizes[0] / (NF * NE);
    afm_fused2<<<B / 2, NTH, 0, stream>>>(xg, wg, wbg, hg, pwg, pbg, (float*)d_out);
}

// Round 3
// 153.368 us; speedup vs baseline: 1.3543x; 1.3543x over previous
//
#include <hip/hip_runtime.h>

#define NF 40
#define NE 128
#define NA 128
#define NP 780        // NF*(NF-1)/2
#define NPT 784       // padded to 49*16
#define NMT 49        // m-tiles of 16 pairs
#define XLD 136       // x LDS row stride in f16: 272B/row -> (row+quad)%8 bank groups, ~2-way max

typedef _Float16 half8 __attribute__((ext_vector_type(8)));
typedef float floatx4 __attribute__((ext_vector_type(4)));

union Shm {
    _Float16 wst[NA][NE];         // 32768 B: f16 W staging, dead after bfrag reg-load
    struct {
        float sc[NPT];            // 3136 B: scores -> exp
        float afmp[16][NE];       // 8192 B: afm partials
    } p2;
};

__global__ __launch_bounds__(256, 2)
void afm_fused3(const float* __restrict__ xg,   // [B, F, E]
                const float* __restrict__ wg,   // [A, E]
                const float* __restrict__ wbg,  // [A]
                const float* __restrict__ hg,   // [1, A]
                const float* __restrict__ pwg,  // [1, E]
                const float* __restrict__ pbg,  // [1]
                float* __restrict__ out)        // [B]
{
    __shared__ Shm u;
    __shared__ _Float16 xs[NF][XLD];            // 10880 B f16 x
    __shared__ unsigned short ij[NPT];          // 1568 B packed (i<<8)|j
    __shared__ float red_max[4], red_sum[4], red_out[2];

    const int tid  = threadIdx.x;
    const int b    = blockIdx.x;
    const int lane = tid & 63;
    const int wid  = tid >> 6;
    const int col  = lane & 15;
    const int quad = (lane >> 4) & 3;

    // ---- stage x[b] as f16 (40 rows x 16 blocks of 8) ----
    const float* xb = xg + (size_t)b * (NF * NE);
    for (int t = tid; t < NF * 16; t += 256) {
        int row = t >> 4, kb = t & 15;
        const float* src = xb + row * NE + kb * 8;
        float4 v0 = *(const float4*)src;
        float4 v1 = *(const float4*)(src + 4);
        half8 h;
        h[0] = (_Float16)v0.x; h[1] = (_Float16)v0.y;
        h[2] = (_Float16)v0.z; h[3] = (_Float16)v0.w;
        h[4] = (_Float16)v1.x; h[5] = (_Float16)v1.y;
        h[6] = (_Float16)v1.z; h[7] = (_Float16)v1.w;
        *(half8*)&xs[row][kb * 8] = h;
    }
    // ---- stage W as f16 (staging only; dead after bfrag load) ----
    for (int t = tid; t < NA * 16; t += 256) {
        int row = t >> 4, kb = t & 15;
        const float* src = wg + row * NE + kb * 8;
        float4 v0 = *(const float4*)src;
        float4 v1 = *(const float4*)(src + 4);
        half8 h;
        h[0] = (_Float16)v0.x; h[1] = (_Float16)v0.y;
        h[2] = (_Float16)v0.z; h[3] = (_Float16)v0.w;
        h[4] = (_Float16)v1.x; h[5] = (_Float16)v1.y;
        h[6] = (_Float16)v1.z; h[7] = (_Float16)v1.w;
        *(half8*)&u.wst[row][kb * 8] = h;
    }
    // ---- pair index table ----
    for (int p = tid; p < NPT; p += 256) {
        unsigned short v = 0;
        if (p < NP) {
            int i = 0, rem = p;
            while (rem >= (NF - 1 - i)) { rem -= (NF - 1 - i); ++i; }
            v = (unsigned short)((i << 8) | (i + 1 + rem));
        }
        ij[p] = v;
    }
    // ---- per-lane epilogue constants (indexed by col) ----
    float wbr[8], hr[8];
#pragma unroll
    for (int n = 0; n < 8; ++n) {
        wbr[n] = wbg[n * 16 + col];
        hr[n]  = hg[n * 16 + col];
    }
    __syncthreads();

    // ---- B-fragments into registers: B[n=col][k=quad*8+j] = W[a][e], f16 ----
    // u.wst is OVERWRITTEN by p2.sc below -> compiler must keep these in VGPRs.
    half8 bfrag[8][4];
#pragma unroll
    for (int n = 0; n < 8; ++n)
#pragma unroll
        for (int k = 0; k < 4; ++k)
            bfrag[n][k] = *(const half8*)&u.wst[n * 16 + col][k * 32 + quad * 8];
    __syncthreads();   // all waves done reading W before anyone writes sc

    // ---- main MFMA loop: S[p,a] = sum_e hp[p,e] * W[a,e] ----
    for (int mt = wid; mt < NMT; mt += 4) {
        const int p0 = mt * 16;
        const int v  = ij[p0 + col];
        const _Float16* xi = &xs[(v >> 8) & 255][0];
        const _Float16* xj = &xs[v & 255][0];

        floatx4 acc[8];
#pragma unroll
        for (int n = 0; n < 8; ++n) acc[n] = (floatx4){0.f, 0.f, 0.f, 0.f};

#pragma unroll
        for (int k = 0; k < 4; ++k) {
            const int koff = k * 32 + quad * 8;
            half8 ai = *(const half8*)(xi + koff);
            half8 aj = *(const half8*)(xj + koff);
            half8 af = ai * aj;                       // 4x v_pk_mul_f16
#pragma unroll
            for (int n = 0; n < 8; ++n)
                acc[n] = __builtin_amdgcn_mfma_f32_16x16x32_f16(af, bfrag[n][k], acc[n], 0, 0, 0);
        }

        // scores[p] = sum_a relu(S[p,a] + wb[a]) * h[a]   (h_b cancels in softmax)
        float ps[4] = {0.f, 0.f, 0.f, 0.f};
#pragma unroll
        for (int n = 0; n < 8; ++n) {
#pragma unroll
            for (int r = 0; r < 4; ++r) {
                float val = acc[n][r] + wbr[n];
                ps[r] += fmaxf(val, 0.f) * hr[n];
            }
        }
#pragma unroll
        for (int r = 0; r < 4; ++r) {
#pragma unroll
            for (int off = 1; off < 16; off <<= 1)
                ps[r] += __shfl_xor(ps[r], off);
        }
        if (col == 0) {
#pragma unroll
            for (int r = 0; r < 4; ++r) {
                int p = p0 + quad * 4 + r;
                if (p < NP) u.p2.sc[p] = ps[r];
            }
        }
    }
    __syncthreads();

    // ---- softmax over 780 pairs (unnormalized; fold 1/sum at the end) ----
    float m = -1e30f;
    for (int p = tid; p < NP; p += 256) m = fmaxf(m, u.p2.sc[p]);
#pragma unroll
    for (int off = 1; off < 64; off <<= 1) m = fmaxf(m, __shfl_xor(m, off));
    if (lane == 0) red_max[wid] = m;
    __syncthreads();
    const float M = fmaxf(fmaxf(red_max[0], red_max[1]), fmaxf(red_max[2], red_max[3]));

    float s = 0.f;
    for (int p = tid; p < NP; p += 256) {
        float e = __expf(u.p2.sc[p] - M);
        u.p2.sc[p] = e;
        s += e;
    }
#pragma unroll
    for (int off = 1; off < 64; off <<= 1) s += __shfl_xor(s, off);
    if (lane == 0) red_sum[wid] = s;
    __syncthreads();

    // ---- afm[e] = sum_p exp_p * xi[e]*xj[e]  (fp32 accum from f16 x) ----
    const int q  = tid >> 4;          // 16 pair-chunks of <=49
    const int kb = tid & 15;          // 8-element e-block
    float a[8];
#pragma unroll
    for (int r = 0; r < 8; ++r) a[r] = 0.f;
    const int pbeg = q * 49;
    const int pend = (pbeg + 49 < NP) ? (pbeg + 49) : NP;
    for (int p = pbeg; p < pend; ++p) {
        int vv = ij[p];
        float w = u.p2.sc[p];
        half8 hi = *(const half8*)&xs[(vv >> 8) & 255][kb * 8];
        half8 hj = *(const half8*)&xs[vv & 255][kb * 8];
        half8 pr = hi * hj;
#pragma unroll
        for (int r = 0; r < 8; ++r) a[r] += w * (float)pr[r];
    }
#pragma unroll
    for (int r = 0; r < 8; ++r) u.p2.afmp[q][kb * 8 + r] = a[r];
    __syncthreads();

    // ---- out[b] = dot(afm_un, pw) / sum_exp + p_b ----
    float vv2 = 0.f;
    if (tid < NE) {
        float acc2 = 0.f;
#pragma unroll
        for (int qq = 0; qq < 16; ++qq) acc2 += u.p2.afmp[qq][tid];
        vv2 = acc2 * pwg[tid];
    }
#pragma unroll
    for (int off = 1; off < 64; off <<= 1) vv2 += __shfl_xor(vv2, off);
    if (tid < NE && lane == 0) red_out[wid] = vv2;
    __syncthreads();
    if (tid == 0) {
        float S   = red_sum[0] + red_sum[1] + red_sum[2] + red_sum[3];
        float tot = red_out[0] + red_out[1];
        out[b] = tot / S + pbg[0];
    }
}

extern "C" void kernel_launch(void* const* d_in, const int* in_sizes, int n_in,
                              void* d_out, int out_size, void* d_ws, size_t ws_size,
                              hipStream_t stream) {
    const float* xg  = (const float*)d_in[0];  // x [B,F,E]
    const float* wg  = (const float*)d_in[1];  // attn_w_w [A,E]
    const float* wbg = (const float*)d_in[2];  // attn_w_b [A]
    const float* hg  = (const float*)d_in[3];  // attn_h_w [1,A]
    // d_in[4] = attn_h_b : constant shift, cancels in softmax
    const float* pwg = (const float*)d_in[5];  // attn_p_w [1,E]
    const float* pbg = (const float*)d_in[6];  // attn_p_b [1]
    const int B = in_sizes[0] / (NF * NE);
    afm_fused3<<<B, 256, 0, stream>>>(xg, wg, wbg, hg, pwg, pbg, (float*)d_out);
}